// Round 1
// baseline (655.941 us; speedup 1.0000x reference)
//
#include <hip/hip_runtime.h>

constexpr int kN  = 16384;
constexpr int kEB = 524288;
constexpr int kET = 262144;
constexpr int kTA = 107;
constexpr float kEps = 1e-5f;
#define HN 256

__device__ __forceinline__ float wsum(float v) {
#pragma unroll
  for (int m = 1; m < 64; m <<= 1) v += __shfl_xor(v, m, 64);
  return v;
}

// ---- per-edge atomic degree + count ----
__global__ __launch_bounds__(256)
void k_edge_prep(const int* __restrict__ col, const float* __restrict__ w,
                 float* __restrict__ deg, int* __restrict__ cnt, int E) {
  int e = blockIdx.x * 256 + threadIdx.x;
  if (e < E) {
    int c = col[e];
    atomicAdd(&deg[c], w[e]);
    atomicAdd(&cnt[c], 1);
  }
}

// ---- single-block exclusive scan over N counts -> base + cursor ----
__global__ __launch_bounds__(256)
void k_scan(const int* __restrict__ cnt, int* __restrict__ base,
            int* __restrict__ cur, int n) {
  __shared__ int part[256];
  int tid = threadIdx.x;
  int per = n >> 8;           // 64
  int i0 = tid * per;
  int s = 0;
  for (int k = 0; k < per; ++k) s += cnt[i0 + k];
  part[tid] = s;
  __syncthreads();
  for (int off = 1; off < 256; off <<= 1) {
    int v = (tid >= off) ? part[tid - off] : 0;
    __syncthreads();
    part[tid] += v;
    __syncthreads();
  }
  int run = (tid == 0) ? 0 : part[tid - 1];
  for (int k = 0; k < per; ++k) {
    base[i0 + k] = run; cur[i0 + k] = run; run += cnt[i0 + k];
  }
  if (tid == 255) base[n] = run;
}

// ---- dis = rsqrt(deg + 1) (self-loop weight 1 folded in) ----
__global__ __launch_bounds__(256)
void k_dis(const float* __restrict__ deg, float* __restrict__ dis, int n) {
  int i = blockIdx.x * 256 + threadIdx.x;
  if (i < n) {
    float d = deg[i] + 1.0f;
    dis[i] = (d > 0.f) ? rsqrtf(d) : 0.f;
  }
}

// ---- CSR fill: per edge store (src, norm) packed ----
__global__ __launch_bounds__(256)
void k_fill(const int* __restrict__ row, const int* __restrict__ col,
            const float* __restrict__ w, const float* __restrict__ dis,
            int* __restrict__ cur, int2* __restrict__ csr, int E) {
  int e = blockIdx.x * 256 + threadIdx.x;
  if (e < E) {
    int c = col[e], r = row[e];
    float nrm = dis[r] * w[e] * dis[c];
    int pos = atomicAdd(&cur[c], 1);
    csr[pos] = make_int2(r, __float_as_int(nrm));
  }
}

// ---- fp32 GEMM C[M,256] = A[M,256] @ W[256,256], 64x64x32 tiles ----
__global__ __launch_bounds__(256)
void k_gemm(const float* __restrict__ A, const float* __restrict__ W,
            float* __restrict__ C) {
  __shared__ float As[32][68];   // [k][m], stride 68 keeps 16B align + spreads banks
  __shared__ float Bs[32][64];   // [k][n]
  int tid = threadIdx.x;
  int tx = tid & 15, ty = tid >> 4;
  int row0 = blockIdx.y * 64, col0 = blockIdx.x * 64;
  float acc[4][4];
#pragma unroll
  for (int i = 0; i < 4; ++i)
#pragma unroll
    for (int j = 0; j < 4; ++j) acc[i][j] = 0.f;

  for (int k0 = 0; k0 < 256; k0 += 32) {
#pragma unroll
    for (int p = 0; p < 2; ++p) {
      int q = tid + (p << 8);
      int r = q >> 3, c4 = (q & 7) << 2;
      float4 a = *(const float4*)(A + (size_t)(row0 + r) * 256 + k0 + c4);
      As[c4 + 0][r] = a.x; As[c4 + 1][r] = a.y;
      As[c4 + 2][r] = a.z; As[c4 + 3][r] = a.w;
    }
#pragma unroll
    for (int p = 0; p < 2; ++p) {
      int q = tid + (p << 8);
      int r = q >> 4, c4 = (q & 15) << 2;
      *(float4*)(&Bs[r][c4]) = *(const float4*)(W + (size_t)(k0 + r) * 256 + col0 + c4);
    }
    __syncthreads();
#pragma unroll
    for (int k = 0; k < 32; ++k) {
      float4 a = *(const float4*)(&As[k][ty << 2]);
      float4 b = *(const float4*)(&Bs[k][tx << 2]);
      acc[0][0] += a.x * b.x; acc[0][1] += a.x * b.y; acc[0][2] += a.x * b.z; acc[0][3] += a.x * b.w;
      acc[1][0] += a.y * b.x; acc[1][1] += a.y * b.y; acc[1][2] += a.y * b.z; acc[1][3] += a.y * b.w;
      acc[2][0] += a.z * b.x; acc[2][1] += a.z * b.y; acc[2][2] += a.z * b.z; acc[2][3] += a.z * b.w;
      acc[3][0] += a.w * b.x; acc[3][1] += a.w * b.y; acc[3][2] += a.w * b.z; acc[3][3] += a.w * b.w;
    }
    __syncthreads();
  }
#pragma unroll
  for (int i = 0; i < 4; ++i) {
    float4 o = make_float4(acc[i][0], acc[i][1], acc[i][2], acc[i][3]);
    *(float4*)(C + (size_t)(row0 + (ty << 2) + i) * 256 + col0 + (tx << 2)) = o;
  }
}

// ---- temporal edge MLP: temp_w[e] = relu(LN(attr@w1+b1)) @ w2 + b2 ----
__global__ __launch_bounds__(256)
void k_proj(const float* __restrict__ attr, const float* __restrict__ w1,
            const float* __restrict__ b1, const float* __restrict__ pg,
            const float* __restrict__ pbeta, const float* __restrict__ w2,
            const float* __restrict__ b2, float* __restrict__ temp_w) {
  __shared__ float attr_lds[kTA * 16];   // [t][j]
  __shared__ float h_lds[16 * 256];      // [j][c]
  int tid = threadIdx.x;
  int e0 = blockIdx.x * 16;
  for (int idx = tid; idx < 16 * kTA; idx += 256) {
    int j = idx / kTA, t = idx - j * kTA;
    attr_lds[t * 16 + j] = attr[(size_t)(e0 + j) * kTA + t];
  }
  __syncthreads();
  float acc[16];
#pragma unroll
  for (int j = 0; j < 16; ++j) acc[j] = 0.f;
#pragma unroll 4
  for (int t = 0; t < kTA; ++t) {
    float w = w1[(size_t)t * 256 + tid];       // L2-resident (109 KB)
    const float4 a0 = *(const float4*)(attr_lds + t * 16 + 0);
    const float4 a1 = *(const float4*)(attr_lds + t * 16 + 4);
    const float4 a2 = *(const float4*)(attr_lds + t * 16 + 8);
    const float4 a3 = *(const float4*)(attr_lds + t * 16 + 12);
    acc[0]  += w * a0.x; acc[1]  += w * a0.y; acc[2]  += w * a0.z; acc[3]  += w * a0.w;
    acc[4]  += w * a1.x; acc[5]  += w * a1.y; acc[6]  += w * a1.z; acc[7]  += w * a1.w;
    acc[8]  += w * a2.x; acc[9]  += w * a2.y; acc[10] += w * a2.z; acc[11] += w * a2.w;
    acc[12] += w * a3.x; acc[13] += w * a3.y; acc[14] += w * a3.z; acc[15] += w * a3.w;
  }
  float bias = b1[tid];
#pragma unroll
  for (int j = 0; j < 16; ++j) h_lds[j * 256 + tid] = acc[j] + bias;
  __syncthreads();
  int wv = tid >> 6, lane = tid & 63;
  int c = lane << 2;
  float4 g  = *(const float4*)(pg + c);
  float4 be = *(const float4*)(pbeta + c);
  float4 w2v = *(const float4*)(w2 + c);
  float b2s = b2[0];
#pragma unroll
  for (int jj = 0; jj < 4; ++jj) {
    int j = (wv << 2) + jj;
    float4 v = *(const float4*)(h_lds + j * 256 + c);
    float sum = wsum(v.x + v.y + v.z + v.w);
    float ss  = wsum(v.x * v.x + v.y * v.y + v.z * v.z + v.w * v.w);
    float mean = sum * (1.f / 256);
    float inv = rsqrtf(ss * (1.f / 256) - mean * mean + kEps);
    float y0 = fmaxf((v.x - mean) * inv * g.x + be.x, 0.f);
    float y1 = fmaxf((v.y - mean) * inv * g.y + be.y, 0.f);
    float y2 = fmaxf((v.z - mean) * inv * g.z + be.z, 0.f);
    float y3 = fmaxf((v.w - mean) * inv * g.w + be.w, 0.f);
    float d = y0 * w2v.x + y1 * w2v.y + y2 * w2v.z + y3 * w2v.w;
    d = wsum(d);
    if (lane == 0) temp_w[e0 + j] = d + b2s;
  }
}

// ---- fused gather-aggregate + bias + residual + LN + relu (+ final LN) ----
template <int FINAL>
__global__ __launch_bounds__(256)
void k_agg_ln(const float* __restrict__ h, const float* __restrict__ resid,
              const float* __restrict__ x0, const int2* __restrict__ csr,
              const int* __restrict__ basep, const float* __restrict__ dis,
              const float* __restrict__ bias, const float* __restrict__ g1,
              const float* __restrict__ b1, const float* __restrict__ g2,
              const float* __restrict__ b2, float* __restrict__ out) {
  int wave = threadIdx.x >> 6, lane = threadIdx.x & 63;
  int node = (blockIdx.x << 2) + wave;
  int c = lane << 2;
  float di = dis[node];
  const float4 hs = *(const float4*)(h + (size_t)node * HN + c);
  float sl = di * di;
  float4 acc = make_float4(hs.x * sl, hs.y * sl, hs.z * sl, hs.w * sl);
  int e0 = basep[node], e1 = basep[node + 1];
  if (e0 < e1) {
    int2 p = csr[e0];
    for (int k = e0; k < e1; ++k) {
      int2 pn = p;
      if (k + 1 < e1) pn = csr[k + 1];       // prefetch next edge meta
      float nrm = __int_as_float(p.y);
      const float4 hv = *(const float4*)(h + (size_t)p.x * HN + c);
      acc.x += nrm * hv.x; acc.y += nrm * hv.y;
      acc.z += nrm * hv.z; acc.w += nrm * hv.w;
      p = pn;
    }
  }
  float4 bb = *(const float4*)(bias + c);
  float4 rr = *(const float4*)(resid + (size_t)node * HN + c);
  float v0 = acc.x + bb.x + rr.x;
  float v1 = acc.y + bb.y + rr.y;
  float v2 = acc.z + bb.z + rr.z;
  float v3 = acc.w + bb.w + rr.w;
  float sum = wsum(v0 + v1 + v2 + v3);
  float ss  = wsum(v0 * v0 + v1 * v1 + v2 * v2 + v3 * v3);
  float mean = sum * (1.f / HN);
  float inv = rsqrtf(ss * (1.f / HN) - mean * mean + kEps);
  float4 g = *(const float4*)(g1 + c);
  float4 b = *(const float4*)(b1 + c);
  float y0 = fmaxf((v0 - mean) * inv * g.x + b.x, 0.f);
  float y1 = fmaxf((v1 - mean) * inv * g.y + b.y, 0.f);
  float y2 = fmaxf((v2 - mean) * inv * g.z + b.z, 0.f);
  float y3 = fmaxf((v3 - mean) * inv * g.w + b.w, 0.f);
  if (!FINAL) {
    *(float4*)(out + (size_t)node * HN + c) = make_float4(y0, y1, y2, y3);
  } else {
    float4 xx = *(const float4*)(x0 + (size_t)node * HN + c);
    float z0 = y0 + xx.x, z1 = y1 + xx.y, z2 = y2 + xx.z, z3 = y3 + xx.w;
    float s2 = wsum(z0 + z1 + z2 + z3);
    float q2 = wsum(z0 * z0 + z1 * z1 + z2 * z2 + z3 * z3);
    float m2 = s2 * (1.f / HN);
    float i2 = rsqrtf(q2 * (1.f / HN) - m2 * m2 + kEps);
    float4 G = *(const float4*)(g2 + c);
    float4 B = *(const float4*)(b2 + c);
    float o0 = (z0 - m2) * i2 * G.x + B.x;
    float o1 = (z1 - m2) * i2 * G.y + B.y;
    float o2 = (z2 - m2) * i2 * G.z + B.z;
    float o3 = (z3 - m2) * i2 * G.w + B.w;
    *(float4*)(out + (size_t)node * HN + c) = make_float4(o0, o1, o2, o3);
  }
}

extern "C" void kernel_launch(void* const* d_in, const int* in_sizes, int n_in,
                              void* d_out, int out_size, void* d_ws, size_t ws_size,
                              hipStream_t stream) {
  const float* x     = (const float*)d_in[0];
  const int*   bei   = (const int*)d_in[1];
  const float* bew   = (const float*)d_in[2];
  const int*   tei   = (const int*)d_in[3];
  const float* tattr = (const float*)d_in[4];
  const float* Wb    = (const float*)d_in[5];
  const float* bb    = (const float*)d_in[6];
  const float* Wt    = (const float*)d_in[7];
  const float* bt    = (const float*)d_in[8];
  const float* gs    = (const float*)d_in[9];
  const float* bs    = (const float*)d_in[10];
  const float* gt    = (const float*)d_in[11];
  const float* btn   = (const float*)d_in[12];
  const float* pw1   = (const float*)d_in[13];
  const float* pb1   = (const float*)d_in[14];
  const float* pg    = (const float*)d_in[15];
  const float* pbeta = (const float*)d_in[16];
  const float* pw2   = (const float*)d_in[17];
  const float* pb2   = (const float*)d_in[18];
  float* outp = (float*)d_out;

  // bump allocator over d_ws
  size_t off = 0;
  auto alloc = [&](size_t bytes) -> void* {
    void* p = (char*)d_ws + off;
    off += (bytes + 255) & ~(size_t)255;
    return p;
  };
  float* deg_b = (float*)alloc(kN * 4);
  float* deg_t = (float*)alloc(kN * 4);
  int*   cnt_b = (int*)alloc(kN * 4);
  int*   cnt_t = (int*)alloc(kN * 4);        // deg_b..cnt_t contiguous: one memset
  float* dis_b = (float*)alloc(kN * 4);
  float* dis_t = (float*)alloc(kN * 4);
  int*   base_b = (int*)alloc((kN + 1) * 4);
  int*   base_t = (int*)alloc((kN + 1) * 4);
  int*   cur_b  = (int*)alloc(kN * 4);
  int*   cur_t  = (int*)alloc(kN * 4);
  float* tmpw   = (float*)alloc(kET * 4);
  int2*  csr_b  = (int2*)alloc((size_t)kEB * 8);
  int2*  csr_t  = (int2*)alloc((size_t)kET * 8);
  float* hbuf   = (float*)alloc((size_t)kN * HN * 4);
  float* sbuf   = (float*)alloc((size_t)kN * HN * 4);
  (void)ws_size; (void)in_sizes; (void)n_in; (void)out_size;

  hipMemsetAsync(deg_b, 0, (size_t)4 * kN * 4, stream);  // deg_b, deg_t, cnt_b, cnt_t

  // ---- stage 1: bold GCN ----
  k_edge_prep<<<kEB / 256, 256, 0, stream>>>(bei + kEB, bew, deg_b, cnt_b, kEB);
  k_scan<<<1, 256, 0, stream>>>(cnt_b, base_b, cur_b, kN);
  k_dis<<<kN / 256, 256, 0, stream>>>(deg_b, dis_b, kN);
  k_fill<<<kEB / 256, 256, 0, stream>>>(bei, bei + kEB, bew, dis_b, cur_b, csr_b, kEB);
  k_gemm<<<dim3(4, kN / 64), 256, 0, stream>>>(x, Wb, hbuf);
  k_agg_ln<0><<<kN / 4, 256, 0, stream>>>(hbuf, x, nullptr, csr_b, base_b, dis_b,
                                          bb, gs, bs, nullptr, nullptr, sbuf);

  // ---- stage 2: temporal edge weights ----
  k_proj<<<kET / 16, 256, 0, stream>>>(tattr, pw1, pb1, pg, pbeta, pw2, pb2, tmpw);

  // ---- stage 3: temporal GCN + final LN ----
  k_edge_prep<<<kET / 256, 256, 0, stream>>>(tei + kET, tmpw, deg_t, cnt_t, kET);
  k_scan<<<1, 256, 0, stream>>>(cnt_t, base_t, cur_t, kN);
  k_dis<<<kN / 256, 256, 0, stream>>>(deg_t, dis_t, kN);
  k_fill<<<kET / 256, 256, 0, stream>>>(tei, tei + kET, tmpw, dis_t, cur_t, csr_t, kET);
  k_gemm<<<dim3(4, kN / 64), 256, 0, stream>>>(sbuf, Wt, hbuf);
  k_agg_ln<1><<<kN / 4, 256, 0, stream>>>(hbuf, sbuf, x, csr_t, base_t, dis_t,
                                          bt, gt, btn, gs, bs, outp);
}

// Round 2
// 462.336 us; speedup vs baseline: 1.4188x; 1.4188x over previous
//
#include <hip/hip_runtime.h>

constexpr int kN  = 16384;
constexpr int kEB = 524288;
constexpr int kET = 262144;
constexpr int kTA = 107;
constexpr float kEps = 1e-5f;
#define HN 256

typedef __attribute__((ext_vector_type(8))) short short8;
typedef __attribute__((ext_vector_type(4))) float floatx4;

__device__ __forceinline__ float wsum(float v) {
#pragma unroll
  for (int m = 1; m < 64; m <<= 1) v += __shfl_xor(v, m, 64);
  return v;
}

__device__ __forceinline__ unsigned int bf16rn(float f) {
  unsigned int u = __float_as_uint(f);
  return (u + 0x7FFFu + ((u >> 16) & 1u)) >> 16;
}
__device__ __forceinline__ unsigned int pack2(float a, float b) {
  return bf16rn(a) | (bf16rn(b) << 16);
}
// XOR swizzle: spread 16B slots across banks within 8-row (256B-stride) stripes
__device__ __forceinline__ unsigned int swz(unsigned int byte) {
  return byte ^ (((byte >> 8) & 7u) << 4);
}

// ---- per-edge atomic degree + count ----
__global__ __launch_bounds__(256)
void k_edge_prep(const int* __restrict__ col, const float* __restrict__ w,
                 float* __restrict__ deg, int* __restrict__ cnt, int E) {
  int e = blockIdx.x * 256 + threadIdx.x;
  if (e < E) {
    int c = col[e];
    atomicAdd(&deg[c], w[e]);
    atomicAdd(&cnt[c], 1);
  }
}

// ---- single-block exclusive scan over N counts -> base + cursor ----
__global__ __launch_bounds__(256)
void k_scan(const int* __restrict__ cnt, int* __restrict__ base,
            int* __restrict__ cur, int n) {
  __shared__ int part[256];
  int tid = threadIdx.x;
  int per = n >> 8;
  int i0 = tid * per;
  int s = 0;
  for (int k = 0; k < per; ++k) s += cnt[i0 + k];
  part[tid] = s;
  __syncthreads();
  for (int off = 1; off < 256; off <<= 1) {
    int v = (tid >= off) ? part[tid - off] : 0;
    __syncthreads();
    part[tid] += v;
    __syncthreads();
  }
  int run = (tid == 0) ? 0 : part[tid - 1];
  for (int k = 0; k < per; ++k) {
    base[i0 + k] = run; cur[i0 + k] = run; run += cnt[i0 + k];
  }
  if (tid == 255) base[n] = run;
}

__global__ __launch_bounds__(256)
void k_dis(const float* __restrict__ deg, float* __restrict__ dis, int n) {
  int i = blockIdx.x * 256 + threadIdx.x;
  if (i < n) {
    float d = deg[i] + 1.0f;
    dis[i] = (d > 0.f) ? rsqrtf(d) : 0.f;
  }
}

// ---- CSR fill: per edge store (src, norm) packed ----
__global__ __launch_bounds__(256)
void k_fill(const int* __restrict__ row, const int* __restrict__ col,
            const float* __restrict__ w, const float* __restrict__ dis,
            int* __restrict__ cur, int2* __restrict__ csr, int E) {
  int e = blockIdx.x * 256 + threadIdx.x;
  if (e < E) {
    int c = col[e], r = row[e];
    float nrm = dis[r] * w[e] * dis[c];
    int pos = atomicAdd(&cur[c], 1);
    csr[pos] = make_int2(r, __float_as_int(nrm));
  }
}

// ---- bf16-MFMA GEMM: C[M,256] = A[M,256] @ W[256,256], fp32 in/out ----
// 32 rows/block, 4 waves each own 64 cols, K in 2 tiles of 128.
__global__ __launch_bounds__(256)
void k_gemm_mfma(const float* __restrict__ A, const float* __restrict__ W,
                 float* __restrict__ C) {
  __shared__ __align__(16) unsigned short Atile[32 * 128];  // 8 KB, swizzled
  int tid = threadIdx.x;
  int w = tid >> 6, lane = tid & 63, low4 = lane & 15, hi = lane >> 4;
  int row0 = blockIdx.x * 32;
  int colbase = w * 64;

  floatx4 acc[2][4];
#pragma unroll
  for (int rt = 0; rt < 2; ++rt)
#pragma unroll
    for (int nn = 0; nn < 4; ++nn) acc[rt][nn] = (floatx4){0.f, 0.f, 0.f, 0.f};

  for (int kt = 0; kt < 2; ++kt) {
    // B fragments (registers, L2-resident W), k = kt*128 + kk*32 + hi*8 + e
    short8 bfr[4][4];
#pragma unroll
    for (int kk = 0; kk < 4; ++kk)
#pragma unroll
      for (int nn = 0; nn < 4; ++nn) {
        int col = colbase + nn * 16 + low4;
#pragma unroll
        for (int e = 0; e < 8; ++e) {
          int k = kt * 128 + kk * 32 + hi * 8 + e;
          bfr[kk][nn][e] = (short)bf16rn(W[(size_t)k * 256 + col]);
        }
      }
    __syncthreads();   // previous k-tile reads done before overwrite
    // stage A tile fp32 -> bf16 (swizzled)
    for (int i = tid; i < 32 * 32; i += 256) {
      int r = i >> 5, q = i & 31;
      float4 v = *(const float4*)(A + (size_t)(row0 + r) * 256 + kt * 128 + q * 4);
      unsigned int byte = swz((unsigned)(r * 256 + q * 8));
      *(uint2*)((char*)Atile + byte) = make_uint2(pack2(v.x, v.y), pack2(v.z, v.w));
    }
    __syncthreads();
#pragma unroll
    for (int kk = 0; kk < 4; ++kk) {
      short8 afr[2];
#pragma unroll
      for (int rt = 0; rt < 2; ++rt) {
        unsigned int byte = swz((unsigned)((rt * 16 + low4) * 256 + (kk * 32 + hi * 8) * 2));
        afr[rt] = *(const short8*)((const char*)Atile + byte);
      }
#pragma unroll
      for (int rt = 0; rt < 2; ++rt)
#pragma unroll
        for (int nn = 0; nn < 4; ++nn)
          acc[rt][nn] = __builtin_amdgcn_mfma_f32_16x16x32_bf16(afr[rt], bfr[kk][nn],
                                                                acc[rt][nn], 0, 0, 0);
    }
  }
#pragma unroll
  for (int rt = 0; rt < 2; ++rt)
#pragma unroll
    for (int nn = 0; nn < 4; ++nn)
#pragma unroll
      for (int j = 0; j < 4; ++j) {
        int row = row0 + rt * 16 + hi * 4 + j;
        int col = colbase + nn * 16 + low4;
        C[(size_t)row * 256 + col] = acc[rt][nn][j];
      }
}

// ---- temporal edge MLP via MFMA: temp_w = relu(LN(attr@w1+b1))@w2 + b2 ----
// 64 edges/block, K padded 107->128, LN fully in-register + LDS partials.
__global__ __launch_bounds__(256)
void k_proj_mfma(const float* __restrict__ attr, const float* __restrict__ w1,
                 const float* __restrict__ b1, const float* __restrict__ pg,
                 const float* __restrict__ pbeta, const float* __restrict__ w2,
                 const float* __restrict__ b2, float* __restrict__ temp_w) {
  __shared__ __align__(16) unsigned short Atile[64 * 128];  // 16 KB, swizzled
  __shared__ float p1[64][4], p2[64][4];
  __shared__ float2 minv[64];
  int tid = threadIdx.x;
  int w = tid >> 6, lane = tid & 63, low4 = lane & 15, hi = lane >> 4;
  int e0 = blockIdx.x * 64;
  int colbase = w * 64;

  // B fragments of w1 (K=128 zero-padded from 107)
  short8 bfr[4][4];
#pragma unroll
  for (int kk = 0; kk < 4; ++kk)
#pragma unroll
    for (int nn = 0; nn < 4; ++nn) {
      int col = colbase + nn * 16 + low4;
#pragma unroll
      for (int e = 0; e < 8; ++e) {
        int k = kk * 32 + hi * 8 + e;
        float v = (k < kTA) ? w1[(size_t)k * 256 + col] : 0.f;
        bfr[kk][nn][e] = (short)bf16rn(v);
      }
    }

  // zero A tile (covers K-pad), then stage attr fp32->bf16 (swizzled)
  for (int i = tid; i < 64 * 128 / 4; i += 256) ((uint2*)Atile)[i] = make_uint2(0, 0);
  __syncthreads();
  const float* abase = attr + (size_t)e0 * kTA;
  for (int i = tid; i < 64 * kTA; i += 256) {
    int r = i / kTA, k = i - r * kTA;
    unsigned int byte = swz((unsigned)(r * 256 + k * 2));
    *(unsigned short*)((char*)Atile + byte) = (unsigned short)bf16rn(abase[i]);
  }
  __syncthreads();

  floatx4 acc[4][4];
#pragma unroll
  for (int rt = 0; rt < 4; ++rt)
#pragma unroll
    for (int nn = 0; nn < 4; ++nn) acc[rt][nn] = (floatx4){0.f, 0.f, 0.f, 0.f};

#pragma unroll
  for (int kk = 0; kk < 4; ++kk) {
    short8 afr[4];
#pragma unroll
    for (int rt = 0; rt < 4; ++rt) {
      unsigned int byte = swz((unsigned)((rt * 16 + low4) * 256 + (kk * 32 + hi * 8) * 2));
      afr[rt] = *(const short8*)((const char*)Atile + byte);
    }
#pragma unroll
    for (int rt = 0; rt < 4; ++rt)
#pragma unroll
      for (int nn = 0; nn < 4; ++nn)
        acc[rt][nn] = __builtin_amdgcn_mfma_f32_16x16x32_bf16(afr[rt], bfr[kk][nn],
                                                              acc[rt][nn], 0, 0, 0);
  }

  // per-col params for this lane
  float b1v[4], gv[4], bev[4], w2v[4];
#pragma unroll
  for (int nn = 0; nn < 4; ++nn) {
    int col = colbase + nn * 16 + low4;
    b1v[nn] = b1[col]; gv[nn] = pg[col]; bev[nn] = pbeta[col]; w2v[nn] = w2[col];
  }
  float b2s = b2[0];

  // partial row sums (this wave's 64-col slice)
#pragma unroll
  for (int rt = 0; rt < 4; ++rt)
#pragma unroll
    for (int j = 0; j < 4; ++j) {
      float s1 = 0.f, s2 = 0.f;
#pragma unroll
      for (int nn = 0; nn < 4; ++nn) {
        float hv = acc[rt][nn][j] + b1v[nn];
        s1 += hv; s2 += hv * hv;
      }
#pragma unroll
      for (int m = 1; m < 16; m <<= 1) {
        s1 += __shfl_xor(s1, m, 64);
        s2 += __shfl_xor(s2, m, 64);
      }
      if (low4 == 0) {
        int row = rt * 16 + hi * 4 + j;
        p1[row][w] = s1; p2[row][w] = s2;
      }
    }
  __syncthreads();
  if (tid < 64) {
    int row = tid;
    float s1 = p1[row][0] + p1[row][1] + p1[row][2] + p1[row][3];
    float s2 = p2[row][0] + p2[row][1] + p2[row][2] + p2[row][3];
    float mean = s1 * (1.f / 256);
    float inv = rsqrtf(s2 * (1.f / 256) - mean * mean + kEps);
    minv[row] = make_float2(mean, inv);
  }
  __syncthreads();
  // relu(LN(h)) . w2, partial per wave then cross-wave reduce
#pragma unroll
  for (int rt = 0; rt < 4; ++rt)
#pragma unroll
    for (int j = 0; j < 4; ++j) {
      int row = rt * 16 + hi * 4 + j;
      float2 mi = minv[row];
      float d = 0.f;
#pragma unroll
      for (int nn = 0; nn < 4; ++nn) {
        float hv = acc[rt][nn][j] + b1v[nn];
        float y = fmaxf((hv - mi.x) * mi.y * gv[nn] + bev[nn], 0.f);
        d += y * w2v[nn];
      }
#pragma unroll
      for (int m = 1; m < 16; m <<= 1) d += __shfl_xor(d, m, 64);
      if (low4 == 0) p1[row][w] = d;
    }
  __syncthreads();
  if (tid < 64) {
    int row = tid;
    temp_w[e0 + row] = p1[row][0] + p1[row][1] + p1[row][2] + p1[row][3] + b2s;
  }
}

// ---- fused gather-aggregate + bias + residual + LN + relu (+ final LN) ----
template <int FINAL>
__global__ __launch_bounds__(256)
void k_agg_ln(const float* __restrict__ h, const float* __restrict__ resid,
              const float* __restrict__ x0, const int2* __restrict__ csr,
              const int* __restrict__ basep, const float* __restrict__ dis,
              const float* __restrict__ bias, const float* __restrict__ g1,
              const float* __restrict__ b1, const float* __restrict__ g2,
              const float* __restrict__ b2, float* __restrict__ out) {
  int wave = threadIdx.x >> 6, lane = threadIdx.x & 63;
  int node = (blockIdx.x << 2) + wave;
  int c = lane << 2;
  float di = dis[node];
  const float4 hs = *(const float4*)(h + (size_t)node * HN + c);
  float sl = di * di;
  float4 acc = make_float4(hs.x * sl, hs.y * sl, hs.z * sl, hs.w * sl);
  int e0 = basep[node], e1 = basep[node + 1];
  if (e0 < e1) {
    int2 p = csr[e0];
    for (int k = e0; k < e1; ++k) {
      int2 pn = p;
      if (k + 1 < e1) pn = csr[k + 1];
      float nrm = __int_as_float(p.y);
      const float4 hv = *(const float4*)(h + (size_t)p.x * HN + c);
      acc.x += nrm * hv.x; acc.y += nrm * hv.y;
      acc.z += nrm * hv.z; acc.w += nrm * hv.w;
      p = pn;
    }
  }
  float4 bb = *(const float4*)(bias + c);
  float4 rr = *(const float4*)(resid + (size_t)node * HN + c);
  float v0 = acc.x + bb.x + rr.x;
  float v1 = acc.y + bb.y + rr.y;
  float v2 = acc.z + bb.z + rr.z;
  float v3 = acc.w + bb.w + rr.w;
  float sum = wsum(v0 + v1 + v2 + v3);
  float ss  = wsum(v0 * v0 + v1 * v1 + v2 * v2 + v3 * v3);
  float mean = sum * (1.f / HN);
  float inv = rsqrtf(ss * (1.f / HN) - mean * mean + kEps);
  float4 g = *(const float4*)(g1 + c);
  float4 b = *(const float4*)(b1 + c);
  float y0 = fmaxf((v0 - mean) * inv * g.x + b.x, 0.f);
  float y1 = fmaxf((v1 - mean) * inv * g.y + b.y, 0.f);
  float y2 = fmaxf((v2 - mean) * inv * g.z + b.z, 0.f);
  float y3 = fmaxf((v3 - mean) * inv * g.w + b.w, 0.f);
  if (!FINAL) {
    *(float4*)(out + (size_t)node * HN + c) = make_float4(y0, y1, y2, y3);
  } else {
    float4 xx = *(const float4*)(x0 + (size_t)node * HN + c);
    float z0 = y0 + xx.x, z1 = y1 + xx.y, z2 = y2 + xx.z, z3 = y3 + xx.w;
    float s2 = wsum(z0 + z1 + z2 + z3);
    float q2 = wsum(z0 * z0 + z1 * z1 + z2 * z2 + z3 * z3);
    float m2 = s2 * (1.f / HN);
    float i2 = rsqrtf(q2 * (1.f / HN) - m2 * m2 + kEps);
    float4 G = *(const float4*)(g2 + c);
    float4 B = *(const float4*)(b2 + c);
    float o0 = (z0 - m2) * i2 * G.x + B.x;
    float o1 = (z1 - m2) * i2 * G.y + B.y;
    float o2 = (z2 - m2) * i2 * G.z + B.z;
    float o3 = (z3 - m2) * i2 * G.w + B.w;
    *(float4*)(out + (size_t)node * HN + c) = make_float4(o0, o1, o2, o3);
  }
}

extern "C" void kernel_launch(void* const* d_in, const int* in_sizes, int n_in,
                              void* d_out, int out_size, void* d_ws, size_t ws_size,
                              hipStream_t stream) {
  const float* x     = (const float*)d_in[0];
  const int*   bei   = (const int*)d_in[1];
  const float* bew   = (const float*)d_in[2];
  const int*   tei   = (const int*)d_in[3];
  const float* tattr = (const float*)d_in[4];
  const float* Wb    = (const float*)d_in[5];
  const float* bb    = (const float*)d_in[6];
  const float* Wt    = (const float*)d_in[7];
  const float* bt    = (const float*)d_in[8];
  const float* gs    = (const float*)d_in[9];
  const float* bs    = (const float*)d_in[10];
  const float* gt    = (const float*)d_in[11];
  const float* btn   = (const float*)d_in[12];
  const float* pw1   = (const float*)d_in[13];
  const float* pb1   = (const float*)d_in[14];
  const float* pg    = (const float*)d_in[15];
  const float* pbeta = (const float*)d_in[16];
  const float* pw2   = (const float*)d_in[17];
  const float* pb2   = (const float*)d_in[18];
  float* outp = (float*)d_out;

  size_t off = 0;
  auto alloc = [&](size_t bytes) -> void* {
    void* p = (char*)d_ws + off;
    off += (bytes + 255) & ~(size_t)255;
    return p;
  };
  float* deg_b = (float*)alloc(kN * 4);
  float* deg_t = (float*)alloc(kN * 4);
  int*   cnt_b = (int*)alloc(kN * 4);
  int*   cnt_t = (int*)alloc(kN * 4);
  float* dis_b = (float*)alloc(kN * 4);
  float* dis_t = (float*)alloc(kN * 4);
  int*   base_b = (int*)alloc((kN + 1) * 4);
  int*   base_t = (int*)alloc((kN + 1) * 4);
  int*   cur_b  = (int*)alloc(kN * 4);
  int*   cur_t  = (int*)alloc(kN * 4);
  float* tmpw   = (float*)alloc(kET * 4);
  int2*  csr_b  = (int2*)alloc((size_t)kEB * 8);
  int2*  csr_t  = (int2*)alloc((size_t)kET * 8);
  float* hbuf   = (float*)alloc((size_t)kN * HN * 4);
  float* sbuf   = (float*)alloc((size_t)kN * HN * 4);
  (void)ws_size; (void)in_sizes; (void)n_in; (void)out_size;

  hipMemsetAsync(deg_b, 0, (size_t)4 * kN * 4, stream);  // deg_b, deg_t, cnt_b, cnt_t

  // ---- stage 1: bold GCN ----
  k_edge_prep<<<kEB / 256, 256, 0, stream>>>(bei + kEB, bew, deg_b, cnt_b, kEB);
  k_scan<<<1, 256, 0, stream>>>(cnt_b, base_b, cur_b, kN);
  k_dis<<<kN / 256, 256, 0, stream>>>(deg_b, dis_b, kN);
  k_fill<<<kEB / 256, 256, 0, stream>>>(bei, bei + kEB, bew, dis_b, cur_b, csr_b, kEB);
  k_gemm_mfma<<<kN / 32, 256, 0, stream>>>(x, Wb, hbuf);
  k_agg_ln<0><<<kN / 4, 256, 0, stream>>>(hbuf, x, nullptr, csr_b, base_b, dis_b,
                                          bb, gs, bs, nullptr, nullptr, sbuf);

  // ---- stage 2: temporal edge weights ----
  k_proj_mfma<<<kET / 64, 256, 0, stream>>>(tattr, pw1, pb1, pg, pbeta, pw2, pb2, tmpw);

  // ---- stage 3: temporal GCN + final LN ----
  k_edge_prep<<<kET / 256, 256, 0, stream>>>(tei + kET, tmpw, deg_t, cnt_t, kET);
  k_scan<<<1, 256, 0, stream>>>(cnt_t, base_t, cur_t, kN);
  k_dis<<<kN / 256, 256, 0, stream>>>(deg_t, dis_t, kN);
  k_fill<<<kET / 256, 256, 0, stream>>>(tei, tei + kET, tmpw, dis_t, cur_t, csr_t, kET);
  k_gemm_mfma<<<kN / 32, 256, 0, stream>>>(sbuf, Wt, hbuf);
  k_agg_ln<1><<<kN / 4, 256, 0, stream>>>(hbuf, sbuf, x, csr_t, base_t, dis_t,
                                          bt, gt, btn, gs, bs, outp);
}

// Round 3
// 385.452 us; speedup vs baseline: 1.7017x; 1.1995x over previous
//
#include <hip/hip_runtime.h>

constexpr int kN  = 16384;
constexpr int kEB = 524288;
constexpr int kET = 262144;
constexpr int kTA = 107;
constexpr float kEps = 1e-5f;
#define HN 256

typedef __attribute__((ext_vector_type(8))) short short8;
typedef __attribute__((ext_vector_type(4))) float floatx4;
typedef unsigned short u16;
typedef unsigned int u32;

#define GLOAD_LDS16(gp, lp)                                                    \
  __builtin_amdgcn_global_load_lds(                                            \
      (const __attribute__((address_space(1))) u32*)(gp),                      \
      (__attribute__((address_space(3))) u32*)(lp), 16, 0, 0)

__device__ __forceinline__ float wsum(float v) {
#pragma unroll
  for (int m = 1; m < 64; m <<= 1) v += __shfl_xor(v, m, 64);
  return v;
}

__device__ __forceinline__ u32 bf16rn(float f) {
  u32 u = __float_as_uint(f);
  return (u + 0x7FFFu + ((u >> 16) & 1u)) >> 16;
}
__device__ __forceinline__ u32 pack2(float a, float b) {
  return bf16rn(a) | (bf16rn(b) << 16);
}
__device__ __forceinline__ float bf2f(u16 v) {
  return __uint_as_float(((u32)v) << 16);
}
// XOR swizzle for 256B-row tiles (bits 8-10 -> 4-6) and 512B-row (9-11 -> 4-6)
__device__ __forceinline__ u32 swz256(u32 b) { return b ^ (((b >> 8) & 7u) << 4); }
__device__ __forceinline__ u32 swz512(u32 b) { return b ^ (((b >> 9) & 7u) << 4); }

// ---- pack w1/Wb/Wt into MFMA-fragment-ordered bf16 ----
// layout: [ktile][colTile(16)][lane(64)][e(8)];  k = ktile*32 + (lane>>4)*8 + e,
// col = colTile*16 + (lane&15)
__global__ __launch_bounds__(256)
void k_pack(const float* __restrict__ w1, const float* __restrict__ Wb,
            const float* __restrict__ Wt, u16* __restrict__ pk1,
            u16* __restrict__ pkb, u16* __restrict__ pkt) {
  int idx = blockIdx.x * 256 + threadIdx.x;
  if (idx < 32768) {                       // w1: K=128 padded from 107
    int e = idx & 7, lane = (idx >> 3) & 63, ct = (idx >> 9) & 15, kk = idx >> 13;
    int k = kk * 32 + (lane >> 4) * 8 + e, col = ct * 16 + (lane & 15);
    pk1[idx] = (u16)(k < kTA ? bf16rn(w1[(size_t)k * 256 + col]) : 0);
  } else {
    int j = idx - 32768;
    const float* W = (j < 65536) ? Wb : Wt;
    u16* pk = (j < 65536) ? pkb : pkt;
    int t = j & 65535;
    int e = t & 7, lane = (t >> 3) & 63, ct = (t >> 9) & 15, kt = t >> 13;
    int k = kt * 32 + (lane >> 4) * 8 + e, col = ct * 16 + (lane & 15);
    pk[t] = (u16)bf16rn(W[(size_t)k * 256 + col]);
  }
}

// ---- fp32 -> bf16 convert (x -> xb), 8 elements/thread ----
__global__ __launch_bounds__(256)
void k_cvt(const float* __restrict__ in, u16* __restrict__ out) {
  size_t i = (size_t)(blockIdx.x * 256 + threadIdx.x) * 8;
  float4 a = *(const float4*)(in + i);
  float4 b = *(const float4*)(in + i + 4);
  uint4 o = make_uint4(pack2(a.x, a.y), pack2(a.z, a.w),
                       pack2(b.x, b.y), pack2(b.z, b.w));
  *(uint4*)(out + i) = o;
}

// ---- fused edge prep for both graphs: degree + count ----
__global__ __launch_bounds__(256)
void k_edge_prep_both(const int* __restrict__ bcol, const float* __restrict__ bw,
                      const int* __restrict__ tcol, const float* __restrict__ tw,
                      float* __restrict__ deg_b, int* __restrict__ cnt_b,
                      float* __restrict__ deg_t, int* __restrict__ cnt_t) {
  int e = blockIdx.x * 256 + threadIdx.x;
  if (e < kEB) {
    int c = bcol[e];
    atomicAdd(&deg_b[c], bw[e]);
    atomicAdd(&cnt_b[c], 1);
  } else {
    int t = e - kEB;
    int c = tcol[t];
    atomicAdd(&deg_t[c], tw[t]);
    atomicAdd(&cnt_t[c], 1);
  }
}

// ---- exclusive scan (one block per graph) ----
__global__ __launch_bounds__(256)
void k_scan_both(const int* __restrict__ cnt_b, int* __restrict__ base_b,
                 int* __restrict__ cur_b, const int* __restrict__ cnt_t,
                 int* __restrict__ base_t, int* __restrict__ cur_t) {
  const int* cnt = blockIdx.x ? cnt_t : cnt_b;
  int* base = blockIdx.x ? base_t : base_b;
  int* cur  = blockIdx.x ? cur_t : cur_b;
  __shared__ int part[256];
  int tid = threadIdx.x;
  int per = kN >> 8;
  int i0 = tid * per;
  int s = 0;
  for (int k = 0; k < per; ++k) s += cnt[i0 + k];
  part[tid] = s;
  __syncthreads();
  for (int off = 1; off < 256; off <<= 1) {
    int v = (tid >= off) ? part[tid - off] : 0;
    __syncthreads();
    part[tid] += v;
    __syncthreads();
  }
  int run = (tid == 0) ? 0 : part[tid - 1];
  for (int k = 0; k < per; ++k) {
    base[i0 + k] = run; cur[i0 + k] = run; run += cnt[i0 + k];
  }
  if (tid == 255) base[kN] = run;
}

__global__ __launch_bounds__(256)
void k_dis_both(const float* __restrict__ deg_b, float* __restrict__ dis_b,
                const float* __restrict__ deg_t, float* __restrict__ dis_t) {
  int i = blockIdx.x * 256 + threadIdx.x;
  if (i < kN) {
    float d = deg_b[i] + 1.0f;
    dis_b[i] = (d > 0.f) ? rsqrtf(d) : 0.f;
  } else {
    int t = i - kN;
    float d = deg_t[t] + 1.0f;
    dis_t[t] = (d > 0.f) ? rsqrtf(d) : 0.f;
  }
}

// ---- CSR fill for both graphs: per edge store (src, norm) packed ----
__global__ __launch_bounds__(256)
void k_fill_both(const int* __restrict__ bei, const float* __restrict__ bw,
                 const float* __restrict__ dis_b, int* __restrict__ cur_b,
                 int2* __restrict__ csr_b, const int* __restrict__ tei,
                 const float* __restrict__ tw, const float* __restrict__ dis_t,
                 int* __restrict__ cur_t, int2* __restrict__ csr_t) {
  int e = blockIdx.x * 256 + threadIdx.x;
  if (e < kEB) {
    int r = bei[e], c = bei[kEB + e];
    float nrm = dis_b[r] * bw[e] * dis_b[c];
    int pos = atomicAdd(&cur_b[c], 1);
    csr_b[pos] = make_int2(r, __float_as_int(nrm));
  } else {
    int t = e - kEB;
    int r = tei[t], c = tei[kET + t];
    float nrm = dis_t[r] * tw[t] * dis_t[c];
    int pos = atomicAdd(&cur_t[c], 1);
    csr_t[pos] = make_int2(r, __float_as_int(nrm));
  }
}

// ---- bf16-MFMA GEMM: Cb[M,256] = Ab[M,256] @ W, all bf16 (fp32 accum) ----
// 32 rows/block, 4 waves x 64 cols, packed W fragments, A via global_load_lds.
__global__ __launch_bounds__(256)
void k_gemm_mfma(const u16* __restrict__ Ab, const u16* __restrict__ pkW,
                 u16* __restrict__ Cb) {
  __shared__ __align__(16) u16 Atile[32 * 256];   // 16 KB, swizzled (512B rows)
  int tid = threadIdx.x;
  int w = tid >> 6, lane = tid & 63, low4 = lane & 15, hi = lane >> 4;
  int row0 = blockIdx.x * 32;

  const char* asrc = (const char*)(Ab + (size_t)row0 * 256);
#pragma unroll
  for (int i = 0; i < 4; ++i) {
    u32 d = (u32)(((i * 4 + w) * 64 + lane) * 16);
    GLOAD_LDS16(asrc + swz512(d), (char*)Atile + (i * 4 + w) * 1024);
  }

  floatx4 acc[2][4];
#pragma unroll
  for (int rt = 0; rt < 2; ++rt)
#pragma unroll
    for (int nn = 0; nn < 4; ++nn) acc[rt][nn] = (floatx4){0.f, 0.f, 0.f, 0.f};

  __syncthreads();   // drains vmcnt -> A tile ready

#pragma unroll
  for (int kt = 0; kt < 8; ++kt) {
    short8 bfr[4];
    const u16* pw = pkW + ((size_t)(kt * 16 + w * 4) * 64 + lane) * 8;
#pragma unroll
    for (int nn = 0; nn < 4; ++nn) bfr[nn] = *(const short8*)(pw + nn * 512);
    short8 afr[2];
#pragma unroll
    for (int rt = 0; rt < 2; ++rt) {
      u32 p = (u32)((rt * 16 + low4) * 512 + (kt * 32 + hi * 8) * 2);
      afr[rt] = *(const short8*)((const char*)Atile + swz512(p));
    }
#pragma unroll
    for (int rt = 0; rt < 2; ++rt)
#pragma unroll
      for (int nn = 0; nn < 4; ++nn)
        acc[rt][nn] = __builtin_amdgcn_mfma_f32_16x16x32_bf16(afr[rt], bfr[nn],
                                                              acc[rt][nn], 0, 0, 0);
  }
#pragma unroll
  for (int rt = 0; rt < 2; ++rt)
#pragma unroll
    for (int nn = 0; nn < 4; ++nn)
#pragma unroll
      for (int j = 0; j < 4; ++j) {
        int row = row0 + rt * 16 + hi * 4 + j;
        int col = w * 64 + nn * 16 + low4;
        Cb[(size_t)row * 256 + col] = (u16)bf16rn(acc[rt][nn][j]);
      }
}

// ---- temporal edge MLP via MFMA (packed w1 fragments) ----
__global__ __launch_bounds__(256)
void k_proj_mfma(const float* __restrict__ attr, const u16* __restrict__ pk1,
                 const float* __restrict__ b1, const float* __restrict__ pg,
                 const float* __restrict__ pbeta, const float* __restrict__ w2,
                 const float* __restrict__ b2, float* __restrict__ temp_w) {
  __shared__ __align__(16) u16 Atile[64 * 128];   // 16 KB, swizzled (256B rows)
  __shared__ float p1[64][4], p2[64][4];
  __shared__ float2 minv[64];
  int tid = threadIdx.x;
  int w = tid >> 6, lane = tid & 63, low4 = lane & 15, hi = lane >> 4;
  int e0 = blockIdx.x * 64;

  // stage attr fp32 -> bf16 (K pad 107->128 with zeros), swizzled
  const float* abase = attr + (size_t)e0 * kTA;
  for (int i = tid; i < 64 * 128; i += 256) {
    int r = i >> 7, k = i & 127;
    float v = (k < kTA) ? abase[r * kTA + k] : 0.f;
    *(u16*)((char*)Atile + swz256((u32)(r * 256 + k * 2))) = (u16)bf16rn(v);
  }
  __syncthreads();

  floatx4 acc[4][4];
#pragma unroll
  for (int rt = 0; rt < 4; ++rt)
#pragma unroll
    for (int nn = 0; nn < 4; ++nn) acc[rt][nn] = (floatx4){0.f, 0.f, 0.f, 0.f};

#pragma unroll
  for (int kk = 0; kk < 4; ++kk) {
    short8 bfr[4];
    const u16* pw = pk1 + ((size_t)(kk * 16 + w * 4) * 64 + lane) * 8;
#pragma unroll
    for (int nn = 0; nn < 4; ++nn) bfr[nn] = *(const short8*)(pw + nn * 512);
    short8 afr[4];
#pragma unroll
    for (int rt = 0; rt < 4; ++rt) {
      u32 p = (u32)((rt * 16 + low4) * 256 + (kk * 32 + hi * 8) * 2);
      afr[rt] = *(const short8*)((const char*)Atile + swz256(p));
    }
#pragma unroll
    for (int rt = 0; rt < 4; ++rt)
#pragma unroll
      for (int nn = 0; nn < 4; ++nn)
        acc[rt][nn] = __builtin_amdgcn_mfma_f32_16x16x32_bf16(afr[rt], bfr[nn],
                                                              acc[rt][nn], 0, 0, 0);
  }

  float b1v[4], gv[4], bev[4], w2v[4];
#pragma unroll
  for (int nn = 0; nn < 4; ++nn) {
    int col = w * 64 + nn * 16 + low4;
    b1v[nn] = b1[col]; gv[nn] = pg[col]; bev[nn] = pbeta[col]; w2v[nn] = w2[col];
  }
  float b2s = b2[0];

#pragma unroll
  for (int rt = 0; rt < 4; ++rt)
#pragma unroll
    for (int j = 0; j < 4; ++j) {
      float s1 = 0.f, s2 = 0.f;
#pragma unroll
      for (int nn = 0; nn < 4; ++nn) {
        float hv = acc[rt][nn][j] + b1v[nn];
        s1 += hv; s2 += hv * hv;
      }
#pragma unroll
      for (int m = 1; m < 16; m <<= 1) {
        s1 += __shfl_xor(s1, m, 64);
        s2 += __shfl_xor(s2, m, 64);
      }
      if (low4 == 0) {
        int row = rt * 16 + hi * 4 + j;
        p1[row][w] = s1; p2[row][w] = s2;
      }
    }
  __syncthreads();
  if (tid < 64) {
    float s1 = p1[tid][0] + p1[tid][1] + p1[tid][2] + p1[tid][3];
    float s2 = p2[tid][0] + p2[tid][1] + p2[tid][2] + p2[tid][3];
    float mean = s1 * (1.f / 256);
    float inv = rsqrtf(s2 * (1.f / 256) - mean * mean + kEps);
    minv[tid] = make_float2(mean, inv);
  }
  __syncthreads();
#pragma unroll
  for (int rt = 0; rt < 4; ++rt)
#pragma unroll
    for (int j = 0; j < 4; ++j) {
      int row = rt * 16 + hi * 4 + j;
      float2 mi = minv[row];
      float d = 0.f;
#pragma unroll
      for (int nn = 0; nn < 4; ++nn) {
        float hv = acc[rt][nn][j] + b1v[nn];
        float y = fmaxf((hv - mi.x) * mi.y * gv[nn] + bev[nn], 0.f);
        d += y * w2v[nn];
      }
#pragma unroll
      for (int m = 1; m < 16; m <<= 1) d += __shfl_xor(d, m, 64);
      if (low4 == 0) p1[row][w] = d;
    }
  __syncthreads();
  if (tid < 64)
    temp_w[e0 + tid] = p1[tid][0] + p1[tid][1] + p1[tid][2] + p1[tid][3] + b2s;
}

// ---- fused gather-aggregate (bf16 h) + bias + residual + LN + relu ----
// FINAL=0: resid fp32 (x), out bf16 (sb). FINAL=1: resid bf16 (sb), out fp32.
template <int FINAL>
__global__ __launch_bounds__(256)
void k_agg_ln(const u16* __restrict__ h, const void* __restrict__ residv,
              const float* __restrict__ x0, const int2* __restrict__ csr,
              const int* __restrict__ basep, const float* __restrict__ dis,
              const float* __restrict__ bias, const float* __restrict__ g1,
              const float* __restrict__ b1, const float* __restrict__ g2,
              const float* __restrict__ b2, void* __restrict__ outv) {
  int wave = threadIdx.x >> 6, lane = threadIdx.x & 63;
  int node = (blockIdx.x << 2) + wave;
  int c = lane << 2;
  float di = dis[node];
  ushort4 hs = *(const ushort4*)(h + (size_t)node * HN + c);
  float sl = di * di;
  float4 acc = make_float4(bf2f(hs.x) * sl, bf2f(hs.y) * sl,
                           bf2f(hs.z) * sl, bf2f(hs.w) * sl);
  int e0 = basep[node], e1 = basep[node + 1];
  if (e0 < e1) {
    int2 p = csr[e0];
    for (int k = e0; k < e1; ++k) {
      int2 pn = p;
      if (k + 1 < e1) pn = csr[k + 1];
      float nrm = __int_as_float(p.y);
      ushort4 hv = *(const ushort4*)(h + (size_t)p.x * HN + c);
      acc.x += nrm * bf2f(hv.x); acc.y += nrm * bf2f(hv.y);
      acc.z += nrm * bf2f(hv.z); acc.w += nrm * bf2f(hv.w);
      p = pn;
    }
  }
  float4 bb = *(const float4*)(bias + c);
  float4 rr;
  if (!FINAL) {
    rr = *(const float4*)((const float*)residv + (size_t)node * HN + c);
  } else {
    ushort4 rv = *(const ushort4*)((const u16*)residv + (size_t)node * HN + c);
    rr = make_float4(bf2f(rv.x), bf2f(rv.y), bf2f(rv.z), bf2f(rv.w));
  }
  float v0 = acc.x + bb.x + rr.x;
  float v1 = acc.y + bb.y + rr.y;
  float v2 = acc.z + bb.z + rr.z;
  float v3 = acc.w + bb.w + rr.w;
  float sum = wsum(v0 + v1 + v2 + v3);
  float ss  = wsum(v0 * v0 + v1 * v1 + v2 * v2 + v3 * v3);
  float mean = sum * (1.f / HN);
  float inv = rsqrtf(ss * (1.f / HN) - mean * mean + kEps);
  float4 g = *(const float4*)(g1 + c);
  float4 b = *(const float4*)(b1 + c);
  float y0 = fmaxf((v0 - mean) * inv * g.x + b.x, 0.f);
  float y1 = fmaxf((v1 - mean) * inv * g.y + b.y, 0.f);
  float y2 = fmaxf((v2 - mean) * inv * g.z + b.z, 0.f);
  float y3 = fmaxf((v3 - mean) * inv * g.w + b.w, 0.f);
  if (!FINAL) {
    uint2 o = make_uint2(pack2(y0, y1), pack2(y2, y3));
    *(uint2*)((u16*)outv + (size_t)node * HN + c) = o;
  } else {
    float4 xx = *(const float4*)(x0 + (size_t)node * HN + c);
    float z0 = y0 + xx.x, z1 = y1 + xx.y, z2 = y2 + xx.z, z3 = y3 + xx.w;
    float s2 = wsum(z0 + z1 + z2 + z3);
    float q2 = wsum(z0 * z0 + z1 * z1 + z2 * z2 + z3 * z3);
    float m2 = s2 * (1.f / HN);
    float i2 = rsqrtf(q2 * (1.f / HN) - m2 * m2 + kEps);
    float4 G = *(const float4*)(g2 + c);
    float4 B = *(const float4*)(b2 + c);
    float4 o = make_float4((z0 - m2) * i2 * G.x + B.x, (z1 - m2) * i2 * G.y + B.y,
                           (z2 - m2) * i2 * G.z + B.z, (z3 - m2) * i2 * G.w + B.w);
    *(float4*)((float*)outv + (size_t)node * HN + c) = o;
  }
}

extern "C" void kernel_launch(void* const* d_in, const int* in_sizes, int n_in,
                              void* d_out, int out_size, void* d_ws, size_t ws_size,
                              hipStream_t stream) {
  const float* x     = (const float*)d_in[0];
  const int*   bei   = (const int*)d_in[1];
  const float* bew   = (const float*)d_in[2];
  const int*   tei   = (const int*)d_in[3];
  const float* tattr = (const float*)d_in[4];
  const float* Wb    = (const float*)d_in[5];
  const float* bb    = (const float*)d_in[6];
  const float* Wt    = (const float*)d_in[7];
  const float* bt    = (const float*)d_in[8];
  const float* gs    = (const float*)d_in[9];
  const float* bs    = (const float*)d_in[10];
  const float* gt    = (const float*)d_in[11];
  const float* btn   = (const float*)d_in[12];
  const float* pw1   = (const float*)d_in[13];
  const float* pb1   = (const float*)d_in[14];
  const float* pg    = (const float*)d_in[15];
  const float* pbeta = (const float*)d_in[16];
  const float* pw2   = (const float*)d_in[17];
  const float* pb2   = (const float*)d_in[18];
  float* outp = (float*)d_out;

  size_t off = 0;
  auto alloc = [&](size_t bytes) -> void* {
    void* p = (char*)d_ws + off;
    off += (bytes + 255) & ~(size_t)255;
    return p;
  };
  float* deg_b = (float*)alloc(kN * 4);
  float* deg_t = (float*)alloc(kN * 4);
  int*   cnt_b = (int*)alloc(kN * 4);
  int*   cnt_t = (int*)alloc(kN * 4);       // deg_b..cnt_t contiguous: one memset
  float* dis_b = (float*)alloc(kN * 4);
  float* dis_t = (float*)alloc(kN * 4);
  int*   base_b = (int*)alloc((kN + 1) * 4);
  int*   base_t = (int*)alloc((kN + 1) * 4);
  int*   cur_b  = (int*)alloc(kN * 4);
  int*   cur_t  = (int*)alloc(kN * 4);
  float* tmpw   = (float*)alloc(kET * 4);
  int2*  csr_b  = (int2*)alloc((size_t)kEB * 8);
  int2*  csr_t  = (int2*)alloc((size_t)kET * 8);
  u16*   pk1 = (u16*)alloc(32768 * 2);
  u16*   pkb = (u16*)alloc(65536 * 2);
  u16*   pkt = (u16*)alloc(65536 * 2);
  u16*   xb  = (u16*)alloc((size_t)kN * HN * 2);
  u16*   hb  = (u16*)alloc((size_t)kN * HN * 2);
  u16*   sb  = (u16*)alloc((size_t)kN * HN * 2);
  (void)ws_size; (void)in_sizes; (void)n_in; (void)out_size;

  hipMemsetAsync(deg_b, 0, (size_t)4 * kN * 4, stream);

  // const prep
  k_pack<<<640, 256, 0, stream>>>(pw1, Wb, Wt, pk1, pkb, pkt);
  k_cvt<<<kN * HN / 8 / 256, 256, 0, stream>>>(x, xb);

  // temporal edge weights (independent of node pipeline)
  k_proj_mfma<<<kET / 64, 256, 0, stream>>>(tattr, pk1, pb1, pg, pbeta, pw2, pb2, tmpw);

  // graph structure for both graphs
  k_edge_prep_both<<<(kEB + kET) / 256, 256, 0, stream>>>(
      bei + kEB, bew, tei + kET, tmpw, deg_b, cnt_b, deg_t, cnt_t);
  k_scan_both<<<2, 256, 0, stream>>>(cnt_b, base_b, cur_b, cnt_t, base_t, cur_t);
  k_dis_both<<<2 * kN / 256, 256, 0, stream>>>(deg_b, dis_b, deg_t, dis_t);
  k_fill_both<<<(kEB + kET) / 256, 256, 0, stream>>>(
      bei, bew, dis_b, cur_b, csr_b, tei, tmpw, dis_t, cur_t, csr_t);

  // stage 1: bold GCN
  k_gemm_mfma<<<kN / 32, 256, 0, stream>>>(xb, pkb, hb);
  k_agg_ln<0><<<kN / 4, 256, 0, stream>>>(hb, x, nullptr, csr_b, base_b, dis_b,
                                          bb, gs, bs, nullptr, nullptr, sb);
  // stage 2: temporal GCN + final LN
  k_gemm_mfma<<<kN / 32, 256, 0, stream>>>(sb, pkt, hb);
  k_agg_ln<1><<<kN / 4, 256, 0, stream>>>(hb, sb, x, csr_t, base_t, dis_t,
                                          bt, gt, btn, gs, bs, outp);
}

// Round 4
// 323.233 us; speedup vs baseline: 2.0293x; 1.1925x over previous
//
#include <hip/hip_runtime.h>

constexpr int kN  = 16384;
constexpr int kEB = 524288;
constexpr int kET = 262144;
constexpr int kTA = 107;
constexpr float kEps = 1e-5f;
#define HN 256

typedef __attribute__((ext_vector_type(8))) short short8;
typedef __attribute__((ext_vector_type(4))) float floatx4;
typedef unsigned short u16;
typedef unsigned int u32;

#define GLOAD_LDS16(gp, lp)                                                    \
  __builtin_amdgcn_global_load_lds(                                            \
      (const __attribute__((address_space(1))) u32*)(gp),                      \
      (__attribute__((address_space(3))) u32*)(lp), 16, 0, 0)

__device__ __forceinline__ float wsum(float v) {
#pragma unroll
  for (int m = 1; m < 64; m <<= 1) v += __shfl_xor(v, m, 64);
  return v;
}

__device__ __forceinline__ u32 bf16rn(float f) {
  u32 u = __float_as_uint(f);
  return (u + 0x7FFFu + ((u >> 16) & 1u)) >> 16;
}
__device__ __forceinline__ u32 pack2(float a, float b) {
  return bf16rn(a) | (bf16rn(b) << 16);
}
__device__ __forceinline__ float bf2f(u16 v) {
  return __uint_as_float(((u32)v) << 16);
}
__device__ __forceinline__ u32 cvtpk(float lo, float hi) {
  u32 r;
  asm volatile("v_cvt_pk_bf16_f32 %0, %1, %2" : "=v"(r) : "v"(lo), "v"(hi));
  return r;
}
// XOR swizzle for 512B-row tiles (bits 9-11 -> 4-6)
__device__ __forceinline__ u32 swz512(u32 b) { return b ^ (((b >> 9) & 7u) << 4); }

// ---- pack w1/Wb/Wt into MFMA-fragment-ordered bf16 ----
// layout: [ktile][colTile(16)][lane(64)][e(8)];  k = ktile*32 + (lane>>4)*8 + e,
// col = colTile*16 + (lane&15)
__global__ __launch_bounds__(256)
void k_pack(const float* __restrict__ w1, const float* __restrict__ Wb,
            const float* __restrict__ Wt, u16* __restrict__ pk1,
            u16* __restrict__ pkb, u16* __restrict__ pkt) {
  int idx = blockIdx.x * 256 + threadIdx.x;
  if (idx < 32768) {                       // w1: K=128 padded from 107
    int e = idx & 7, lane = (idx >> 3) & 63, ct = (idx >> 9) & 15, kk = idx >> 13;
    int k = kk * 32 + (lane >> 4) * 8 + e, col = ct * 16 + (lane & 15);
    pk1[idx] = (u16)(k < kTA ? bf16rn(w1[(size_t)k * 256 + col]) : 0);
  } else {
    int j = idx - 32768;
    const float* W = (j < 65536) ? Wb : Wt;
    u16* pk = (j < 65536) ? pkb : pkt;
    int t = j & 65535;
    int e = t & 7, lane = (t >> 3) & 63, ct = (t >> 9) & 15, kt = t >> 13;
    int k = kt * 32 + (lane >> 4) * 8 + e, col = ct * 16 + (lane & 15);
    pk[t] = (u16)bf16rn(W[(size_t)k * 256 + col]);
  }
}

// ---- fp32 -> bf16 convert (x -> xb), 8 elements/thread ----
__global__ __launch_bounds__(256)
void k_cvt(const float* __restrict__ in, u16* __restrict__ out) {
  size_t i = (size_t)(blockIdx.x * 256 + threadIdx.x) * 8;
  float4 a = *(const float4*)(in + i);
  float4 b = *(const float4*)(in + i + 4);
  uint4 o = make_uint4(pack2(a.x, a.y), pack2(a.z, a.w),
                       pack2(b.x, b.y), pack2(b.z, b.w));
  *(uint4*)(out + i) = o;
}

// ---- fused edge prep for both graphs: degree + count ----
__global__ __launch_bounds__(256)
void k_edge_prep_both(const int* __restrict__ bcol, const float* __restrict__ bw,
                      const int* __restrict__ tcol, const float* __restrict__ tw,
                      float* __restrict__ deg_b, int* __restrict__ cnt_b,
                      float* __restrict__ deg_t, int* __restrict__ cnt_t) {
  int e = blockIdx.x * 256 + threadIdx.x;
  if (e < kEB) {
    int c = bcol[e];
    atomicAdd(&deg_b[c], bw[e]);
    atomicAdd(&cnt_b[c], 1);
  } else {
    int t = e - kEB;
    int c = tcol[t];
    atomicAdd(&deg_t[c], tw[t]);
    atomicAdd(&cnt_t[c], 1);
  }
}

// ---- exclusive scan (one block per graph) ----
__global__ __launch_bounds__(256)
void k_scan_both(const int* __restrict__ cnt_b, int* __restrict__ base_b,
                 int* __restrict__ cur_b, const int* __restrict__ cnt_t,
                 int* __restrict__ base_t, int* __restrict__ cur_t) {
  const int* cnt = blockIdx.x ? cnt_t : cnt_b;
  int* base = blockIdx.x ? base_t : base_b;
  int* cur  = blockIdx.x ? cur_t : cur_b;
  __shared__ int part[256];
  int tid = threadIdx.x;
  int per = kN >> 8;
  int i0 = tid * per;
  int s = 0;
  for (int k = 0; k < per; ++k) s += cnt[i0 + k];
  part[tid] = s;
  __syncthreads();
  for (int off = 1; off < 256; off <<= 1) {
    int v = (tid >= off) ? part[tid - off] : 0;
    __syncthreads();
    part[tid] += v;
    __syncthreads();
  }
  int run = (tid == 0) ? 0 : part[tid - 1];
  for (int k = 0; k < per; ++k) {
    base[i0 + k] = run; cur[i0 + k] = run; run += cnt[i0 + k];
  }
  if (tid == 255) base[kN] = run;
}

__global__ __launch_bounds__(256)
void k_dis_both(const float* __restrict__ deg_b, float* __restrict__ dis_b,
                const float* __restrict__ deg_t, float* __restrict__ dis_t) {
  int i = blockIdx.x * 256 + threadIdx.x;
  if (i < kN) {
    float d = deg_b[i] + 1.0f;
    dis_b[i] = (d > 0.f) ? rsqrtf(d) : 0.f;
  } else {
    int t = i - kN;
    float d = deg_t[t] + 1.0f;
    dis_t[t] = (d > 0.f) ? rsqrtf(d) : 0.f;
  }
}

// ---- CSR fill for both graphs: per edge store (src, norm) packed ----
__global__ __launch_bounds__(256)
void k_fill_both(const int* __restrict__ bei, const float* __restrict__ bw,
                 const float* __restrict__ dis_b, int* __restrict__ cur_b,
                 int2* __restrict__ csr_b, const int* __restrict__ tei,
                 const float* __restrict__ tw, const float* __restrict__ dis_t,
                 int* __restrict__ cur_t, int2* __restrict__ csr_t) {
  int e = blockIdx.x * 256 + threadIdx.x;
  if (e < kEB) {
    int r = bei[e], c = bei[kEB + e];
    float nrm = dis_b[r] * bw[e] * dis_b[c];
    int pos = atomicAdd(&cur_b[c], 1);
    csr_b[pos] = make_int2(r, __float_as_int(nrm));
  } else {
    int t = e - kEB;
    int r = tei[t], c = tei[kET + t];
    float nrm = dis_t[r] * tw[t] * dis_t[c];
    int pos = atomicAdd(&cur_t[c], 1);
    csr_t[pos] = make_int2(r, __float_as_int(nrm));
  }
}

// ---- bf16-MFMA GEMM: Cb[M,256] = Ab[M,256] @ W, all bf16 (fp32 accum) ----
// 32 rows/block, 4 waves x 64 cols, packed W fragments, A via global_load_lds.
__global__ __launch_bounds__(256)
void k_gemm_mfma(const u16* __restrict__ Ab, const u16* __restrict__ pkW,
                 u16* __restrict__ Cb) {
  __shared__ __align__(16) u16 Atile[32 * 256];   // 16 KB, swizzled (512B rows)
  int tid = threadIdx.x;
  int w = tid >> 6, lane = tid & 63, low4 = lane & 15, hi = lane >> 4;
  int row0 = blockIdx.x * 32;

  const char* asrc = (const char*)(Ab + (size_t)row0 * 256);
#pragma unroll
  for (int i = 0; i < 4; ++i) {
    u32 d = (u32)(((i * 4 + w) * 64 + lane) * 16);
    GLOAD_LDS16(asrc + swz512(d), (char*)Atile + (i * 4 + w) * 1024);
  }

  floatx4 acc[2][4];
#pragma unroll
  for (int rt = 0; rt < 2; ++rt)
#pragma unroll
    for (int nn = 0; nn < 4; ++nn) acc[rt][nn] = (floatx4){0.f, 0.f, 0.f, 0.f};

  __syncthreads();   // drains vmcnt -> A tile ready

#pragma unroll
  for (int kt = 0; kt < 8; ++kt) {
    short8 bfr[4];
    const u16* pw = pkW + ((size_t)(kt * 16 + w * 4) * 64 + lane) * 8;
#pragma unroll
    for (int nn = 0; nn < 4; ++nn) bfr[nn] = *(const short8*)(pw + nn * 512);
    short8 afr[2];
#pragma unroll
    for (int rt = 0; rt < 2; ++rt) {
      u32 p = (u32)((rt * 16 + low4) * 512 + (kt * 32 + hi * 8) * 2);
      afr[rt] = *(const short8*)((const char*)Atile + swz512(p));
    }
#pragma unroll
    for (int rt = 0; rt < 2; ++rt)
#pragma unroll
      for (int nn = 0; nn < 4; ++nn)
        acc[rt][nn] = __builtin_amdgcn_mfma_f32_16x16x32_bf16(afr[rt], bfr[nn],
                                                              acc[rt][nn], 0, 0, 0);
  }
#pragma unroll
  for (int rt = 0; rt < 2; ++rt)
#pragma unroll
    for (int nn = 0; nn < 4; ++nn)
#pragma unroll
      for (int j = 0; j < 4; ++j) {
        int row = row0 + rt * 16 + hi * 4 + j;
        int col = w * 64 + nn * 16 + low4;
        Cb[(size_t)row * 256 + col] = (u16)bf16rn(acc[rt][nn][j]);
      }
}

// ---- temporal edge MLP via MFMA ----
// Raw fp32 attr tile staged linearly via global_load_lds (no conversion, no
// padding); A-fragments built from LDS with ds_read_b32 + v_cvt_pk_bf16_f32.
__global__ __launch_bounds__(256)
void k_proj_mfma(const float* __restrict__ attr, const u16* __restrict__ pk1,
                 const float* __restrict__ b1, const float* __restrict__ pg,
                 const float* __restrict__ pbeta, const float* __restrict__ w2,
                 const float* __restrict__ b2, float* __restrict__ temp_w) {
  __shared__ __align__(16) float Af[64 * kTA + 32];   // +32 pad: safe speculation
  __shared__ float p1[64][4], p2[64][4];
  __shared__ float2 minv[64];
  int tid = threadIdx.x;
  int w = tid >> 6, lane = tid & 63, low4 = lane & 15, hi = lane >> 4;
  int e0 = blockIdx.x * 64;

  // stage 64*107 fp32 = 1712 aligned 16B chunks, linear copy, async
  const char* src = (const char*)(attr + (size_t)e0 * kTA);
#pragma unroll
  for (int it = 0; it < 7; ++it) {
    int idx = it * 256 + tid;
    if (idx < 1712)
      GLOAD_LDS16(src + (size_t)idx * 16, (char*)Af + (it * 256 + w * 64) * 16);
  }

  floatx4 acc[4][4];
#pragma unroll
  for (int rt = 0; rt < 4; ++rt)
#pragma unroll
    for (int nn = 0; nn < 4; ++nn) acc[rt][nn] = (floatx4){0.f, 0.f, 0.f, 0.f};

  __syncthreads();   // drains vmcnt -> attr tile ready

#pragma unroll
  for (int kk = 0; kk < 4; ++kk) {
    short8 bfr[4];
    const u16* pw = pk1 + ((size_t)(kk * 16 + w * 4) * 64 + lane) * 8;
#pragma unroll
    for (int nn = 0; nn < 4; ++nn) bfr[nn] = *(const short8*)(pw + nn * 512);
    short8 afr[4];
#pragma unroll
    for (int rt = 0; rt < 4; ++rt) {
      int r = rt * 16 + low4;
      int kb = kk * 32 + hi * 8;
      const float* rowp = Af + r * kTA + kb;
      float v[8];
#pragma unroll
      for (int e = 0; e < 8; ++e) {
        if (kk == 3) v[e] = (kb + e < kTA) ? rowp[e] : 0.f;
        else         v[e] = rowp[e];
      }
      union { short8 s8; uint4 u4; } fr;
      fr.u4 = make_uint4(cvtpk(v[0], v[1]), cvtpk(v[2], v[3]),
                         cvtpk(v[4], v[5]), cvtpk(v[6], v[7]));
      afr[rt] = fr.s8;
    }
#pragma unroll
    for (int rt = 0; rt < 4; ++rt)
#pragma unroll
      for (int nn = 0; nn < 4; ++nn)
        acc[rt][nn] = __builtin_amdgcn_mfma_f32_16x16x32_bf16(afr[rt], bfr[nn],
                                                              acc[rt][nn], 0, 0, 0);
  }

  float b1v[4], gv[4], bev[4], w2v[4];
#pragma unroll
  for (int nn = 0; nn < 4; ++nn) {
    int col = w * 64 + nn * 16 + low4;
    b1v[nn] = b1[col]; gv[nn] = pg[col]; bev[nn] = pbeta[col]; w2v[nn] = w2[col];
  }
  float b2s = b2[0];

#pragma unroll
  for (int rt = 0; rt < 4; ++rt)
#pragma unroll
    for (int j = 0; j < 4; ++j) {
      float s1 = 0.f, s2 = 0.f;
#pragma unroll
      for (int nn = 0; nn < 4; ++nn) {
        float hv = acc[rt][nn][j] + b1v[nn];
        s1 += hv; s2 += hv * hv;
      }
#pragma unroll
      for (int m = 1; m < 16; m <<= 1) {
        s1 += __shfl_xor(s1, m, 64);
        s2 += __shfl_xor(s2, m, 64);
      }
      if (low4 == 0) {
        int row = rt * 16 + hi * 4 + j;
        p1[row][w] = s1; p2[row][w] = s2;
      }
    }
  __syncthreads();
  if (tid < 64) {
    float s1 = p1[tid][0] + p1[tid][1] + p1[tid][2] + p1[tid][3];
    float s2 = p2[tid][0] + p2[tid][1] + p2[tid][2] + p2[tid][3];
    float mean = s1 * (1.f / 256);
    float inv = rsqrtf(s2 * (1.f / 256) - mean * mean + kEps);
    minv[tid] = make_float2(mean, inv);
  }
  __syncthreads();
#pragma unroll
  for (int rt = 0; rt < 4; ++rt)
#pragma unroll
    for (int j = 0; j < 4; ++j) {
      int row = rt * 16 + hi * 4 + j;
      float2 mi = minv[row];
      float d = 0.f;
#pragma unroll
      for (int nn = 0; nn < 4; ++nn) {
        float hv = acc[rt][nn][j] + b1v[nn];
        float y = fmaxf((hv - mi.x) * mi.y * gv[nn] + bev[nn], 0.f);
        d += y * w2v[nn];
      }
#pragma unroll
      for (int m = 1; m < 16; m <<= 1) d += __shfl_xor(d, m, 64);
      if (low4 == 0) p1[row][w] = d;
    }
  __syncthreads();
  if (tid < 64)
    temp_w[e0 + tid] = p1[tid][0] + p1[tid][1] + p1[tid][2] + p1[tid][3] + b2s;
}

// ---- fused gather-aggregate (bf16 h) + bias + residual + LN + relu ----
// FINAL=0: resid fp32 (x), out bf16 (sb). FINAL=1: resid bf16 (sb), out fp32.
template <int FINAL>
__global__ __launch_bounds__(256)
void k_agg_ln(const u16* __restrict__ h, const void* __restrict__ residv,
              const float* __restrict__ x0, const int2* __restrict__ csr,
              const int* __restrict__ basep, const float* __restrict__ dis,
              const float* __restrict__ bias, const float* __restrict__ g1,
              const float* __restrict__ b1, const float* __restrict__ g2,
              const float* __restrict__ b2, void* __restrict__ outv) {
  int wave = threadIdx.x >> 6, lane = threadIdx.x & 63;
  int node = (blockIdx.x << 2) + wave;
  int c = lane << 2;
  float di = dis[node];
  ushort4 hs = *(const ushort4*)(h + (size_t)node * HN + c);
  float sl = di * di;
  float4 acc = make_float4(bf2f(hs.x) * sl, bf2f(hs.y) * sl,
                           bf2f(hs.z) * sl, bf2f(hs.w) * sl);
  int e0 = basep[node], e1 = basep[node + 1];
  if (e0 < e1) {
    int2 p = csr[e0];
    for (int k = e0; k < e1; ++k) {
      int2 pn = p;
      if (k + 1 < e1) pn = csr[k + 1];
      float nrm = __int_as_float(p.y);
      ushort4 hv = *(const ushort4*)(h + (size_t)p.x * HN + c);
      acc.x += nrm * bf2f(hv.x); acc.y += nrm * bf2f(hv.y);
      acc.z += nrm * bf2f(hv.z); acc.w += nrm * bf2f(hv.w);
      p = pn;
    }
  }
  float4 bb = *(const float4*)(bias + c);
  float4 rr;
  if (!FINAL) {
    rr = *(const float4*)((const float*)residv + (size_t)node * HN + c);
  } else {
    ushort4 rv = *(const ushort4*)((const u16*)residv + (size_t)node * HN + c);
    rr = make_float4(bf2f(rv.x), bf2f(rv.y), bf2f(rv.z), bf2f(rv.w));
  }
  float v0 = acc.x + bb.x + rr.x;
  float v1 = acc.y + bb.y + rr.y;
  float v2 = acc.z + bb.z + rr.z;
  float v3 = acc.w + bb.w + rr.w;
  float sum = wsum(v0 + v1 + v2 + v3);
  float ss  = wsum(v0 * v0 + v1 * v1 + v2 * v2 + v3 * v3);
  float mean = sum * (1.f / HN);
  float inv = rsqrtf(ss * (1.f / HN) - mean * mean + kEps);
  float4 g = *(const float4*)(g1 + c);
  float4 b = *(const float4*)(b1 + c);
  float y0 = fmaxf((v0 - mean) * inv * g.x + b.x, 0.f);
  float y1 = fmaxf((v1 - mean) * inv * g.y + b.y, 0.f);
  float y2 = fmaxf((v2 - mean) * inv * g.z + b.z, 0.f);
  float y3 = fmaxf((v3 - mean) * inv * g.w + b.w, 0.f);
  if (!FINAL) {
    uint2 o = make_uint2(pack2(y0, y1), pack2(y2, y3));
    *(uint2*)((u16*)outv + (size_t)node * HN + c) = o;
  } else {
    float4 xx = *(const float4*)(x0 + (size_t)node * HN + c);
    float z0 = y0 + xx.x, z1 = y1 + xx.y, z2 = y2 + xx.z, z3 = y3 + xx.w;
    float s2 = wsum(z0 + z1 + z2 + z3);
    float q2 = wsum(z0 * z0 + z1 * z1 + z2 * z2 + z3 * z3);
    float m2 = s2 * (1.f / HN);
    float i2 = rsqrtf(q2 * (1.f / HN) - m2 * m2 + kEps);
    float4 G = *(const float4*)(g2 + c);
    float4 B = *(const float4*)(b2 + c);
    float4 o = make_float4((z0 - m2) * i2 * G.x + B.x, (z1 - m2) * i2 * G.y + B.y,
                           (z2 - m2) * i2 * G.z + B.z, (z3 - m2) * i2 * G.w + B.w);
    *(float4*)((float*)outv + (size_t)node * HN + c) = o;
  }
}

extern "C" void kernel_launch(void* const* d_in, const int* in_sizes, int n_in,
                              void* d_out, int out_size, void* d_ws, size_t ws_size,
                              hipStream_t stream) {
  const float* x     = (const float*)d_in[0];
  const int*   bei   = (const int*)d_in[1];
  const float* bew   = (const float*)d_in[2];
  const int*   tei   = (const int*)d_in[3];
  const float* tattr = (const float*)d_in[4];
  const float* Wb    = (const float*)d_in[5];
  const float* bb    = (const float*)d_in[6];
  const float* Wt    = (const float*)d_in[7];
  const float* bt    = (const float*)d_in[8];
  const float* gs    = (const float*)d_in[9];
  const float* bs    = (const float*)d_in[10];
  const float* gt    = (const float*)d_in[11];
  const float* btn   = (const float*)d_in[12];
  const float* pw1   = (const float*)d_in[13];
  const float* pb1   = (const float*)d_in[14];
  const float* pg    = (const float*)d_in[15];
  const float* pbeta = (const float*)d_in[16];
  const float* pw2   = (const float*)d_in[17];
  const float* pb2   = (const float*)d_in[18];
  float* outp = (float*)d_out;

  size_t off = 0;
  auto alloc = [&](size_t bytes) -> void* {
    void* p = (char*)d_ws + off;
    off += (bytes + 255) & ~(size_t)255;
    return p;
  };
  float* deg_b = (float*)alloc(kN * 4);
  float* deg_t = (float*)alloc(kN * 4);
  int*   cnt_b = (int*)alloc(kN * 4);
  int*   cnt_t = (int*)alloc(kN * 4);       // deg_b..cnt_t contiguous: one memset
  float* dis_b = (float*)alloc(kN * 4);
  float* dis_t = (float*)alloc(kN * 4);
  int*   base_b = (int*)alloc((kN + 1) * 4);
  int*   base_t = (int*)alloc((kN + 1) * 4);
  int*   cur_b  = (int*)alloc(kN * 4);
  int*   cur_t  = (int*)alloc(kN * 4);
  float* tmpw   = (float*)alloc(kET * 4);
  int2*  csr_b  = (int2*)alloc((size_t)kEB * 8);
  int2*  csr_t  = (int2*)alloc((size_t)kET * 8);
  u16*   pk1 = (u16*)alloc(32768 * 2);
  u16*   pkb = (u16*)alloc(65536 * 2);
  u16*   pkt = (u16*)alloc(65536 * 2);
  u16*   xb  = (u16*)alloc((size_t)kN * HN * 2);
  u16*   hb  = (u16*)alloc((size_t)kN * HN * 2);
  u16*   sb  = (u16*)alloc((size_t)kN * HN * 2);
  (void)ws_size; (void)in_sizes; (void)n_in; (void)out_size;

  hipMemsetAsync(deg_b, 0, (size_t)4 * kN * 4, stream);

  // const prep
  k_pack<<<640, 256, 0, stream>>>(pw1, Wb, Wt, pk1, pkb, pkt);
  k_cvt<<<kN * HN / 8 / 256, 256, 0, stream>>>(x, xb);

  // temporal edge weights (independent of node pipeline)
  k_proj_mfma<<<kET / 64, 256, 0, stream>>>(tattr, pk1, pb1, pg, pbeta, pw2, pb2, tmpw);

  // graph structure for both graphs
  k_edge_prep_both<<<(kEB + kET) / 256, 256, 0, stream>>>(
      bei + kEB, bew, tei + kET, tmpw, deg_b, cnt_b, deg_t, cnt_t);
  k_scan_both<<<2, 256, 0, stream>>>(cnt_b, base_b, cur_b, cnt_t, base_t, cur_t);
  k_dis_both<<<2 * kN / 256, 256, 0, stream>>>(deg_b, dis_b, deg_t, dis_t);
  k_fill_both<<<(kEB + kET) / 256, 256, 0, stream>>>(
      bei, bew, dis_b, cur_b, csr_b, tei, tmpw, dis_t, cur_t, csr_t);

  // stage 1: bold GCN
  k_gemm_mfma<<<kN / 32, 256, 0, stream>>>(xb, pkb, hb);
  k_agg_ln<0><<<kN / 4, 256, 0, stream>>>(hb, x, nullptr, csr_b, base_b, dis_b,
                                          bb, gs, bs, nullptr, nullptr, sb);
  // stage 2: temporal GCN + final LN
  k_gemm_mfma<<<kN / 32, 256, 0, stream>>>(sb, pkt, hb);
  k_agg_ln<1><<<kN / 4, 256, 0, stream>>>(hb, sb, x, csr_t, base_t, dis_t,
                                          bt, gt, btn, gs, bs, outp);
}